// Round 1
// baseline (92.819 us; speedup 1.0000x reference)
//
#include <hip/hip_runtime.h>
#include <math.h>

#define BLOCK 256
#define MAX_KV_LDS 1024   // 8 KiB LDS cap for the staged-contour path

// Winding-angle accumulation for one pixel against kv vertices.
// VP is either an LDS-rooted or global-rooted float2 pointer; keeping the
// call sites separate lets infer-address-spaces emit ds_read / global_load
// instead of flat loads.
template <typename VP>
__device__ __forceinline__ float winding_sum(VP vsrc, int kv, float mx, float my)
{
    float acc = 0.0f;
    float2 v0 = vsrc[0];
    float dx = v0.x - mx;
    float dy = v0.y - my;
    const float d0x = dx, d0y = dy;   // first diff, reused at wraparound

    #pragma unroll 4
    for (int k = 0; k < kv; ++k) {
        float rx, ry;
        if (k + 1 < kv) {
            float2 vn = vsrc[k + 1];
            rx = vn.x - mx;
            ry = vn.y - my;
        } else {
            rx = d0x;
            ry = d0y;
        }
        // cross = diff.y*roll.x - diff.x*roll.y   (matches reference sign)
        float cross = dy * rx - dx * ry;
        float dot   = dx * rx + dy * ry;
        float n2    = (dx * dx + dy * dy) * (rx * rx + ry * ry);
        float cosang = dot / sqrtf(n2);
        cosang = fminf(fmaxf(cosang, -1.0f + 1e-5f), 1.0f - 1e-5f);
        float ang = acosf(cosang);
        float t = 100000.0f * cross;          // K_SIGN
        acc = fmaf(tanhf(t), ang, acc);
        dx = rx;
        dy = ry;
    }
    return acc;
}

__global__ __launch_bounds__(BLOCK)
void contour_mask_kernel(const float2* __restrict__ contour,
                         const int* __restrict__ size_ptr,
                         float* __restrict__ out,
                         int out_size, int in0_elems)
{
    __shared__ float2 verts[MAX_KV_LDS];

    const int size     = *size_ptr;          // scalar (wave-uniform) load
    const int S2       = size * size;
    const int bn_total = out_size / S2;
    const int kv       = in0_elems / (bn_total * 2);

    const int idx     = blockIdx.x * BLOCK + threadIdx.x;
    const int bn0     = (blockIdx.x * BLOCK) / S2;              // bn of lane 0
    const int bn_last = (blockIdx.x * BLOCK + BLOCK - 1) / S2;  // bn of last lane
    const bool use_lds = (kv <= MAX_KV_LDS) && (bn0 == bn_last);

    if (use_lds) {
        for (int i = threadIdx.x; i < kv; i += BLOCK)
            verts[i] = contour[(size_t)bn0 * kv + i];
    }
    __syncthreads();

    if (idx >= out_size) return;

    const int bn = idx / S2;
    const int p  = idx - bn * S2;
    const float inv_size = 1.0f / (float)size;
    const int pi = p / size;
    const int pj = p - pi * size;
    // mesh = meshgrid(g, g, 'ij').reshape(-1,2)/size: channel0 = i/size, channel1 = j/size
    const float mx = (float)pi * inv_size;
    const float my = (float)pj * inv_size;

    float acc;
    if (use_lds)
        acc = winding_sum(verts, kv, mx, my);
    else
        acc = winding_sum(contour + (size_t)bn * kv, kv, mx, my);

    // |sum| / (2*pi), clipped to [0, 1]
    float res = fabsf(acc) * 0.15915494309189535f;
    res = fminf(res, 1.0f);
    out[idx] = res;
}

extern "C" void kernel_launch(void* const* d_in, const int* in_sizes, int n_in,
                              void* d_out, int out_size, void* d_ws, size_t ws_size,
                              hipStream_t stream)
{
    const float2* contour  = (const float2*)d_in[0];
    const int*    size_ptr = (const int*)d_in[1];
    float*        out      = (float*)d_out;

    const int blocks = (out_size + BLOCK - 1) / BLOCK;
    contour_mask_kernel<<<blocks, BLOCK, 0, stream>>>(
        contour, size_ptr, out, out_size, in_sizes[0]);
}

// Round 2
// 76.604 us; speedup vs baseline: 1.2117x; 1.2117x over previous
//
#include <hip/hip_runtime.h>
#include <math.h>

#define BLOCK 256
#define MAX_KV_LDS 1024   // 8 KiB LDS cap for the staged-contour path

// ---- fast approximations (we have 2e-2 absmax slack; these are ~1e-4) ----

// tanh(t) = 1 - 2/(exp(2t)+1); branchless, exact at +/-inf saturation.
__device__ __forceinline__ float fast_tanh(float t)
{
    float e = __expf(2.0f * t);                       // v_mul + v_exp_f32
    return 1.0f - 2.0f * __builtin_amdgcn_rcpf(e + 1.0f);
}

// Abramowitz-Stegun 4.4.45: acos(x) ~ sqrt(1-x)*poly(x), x in [0,1],
// max err 6.7e-5 rad; reflected for x<0.
__device__ __forceinline__ float fast_acos(float x)
{
    float y = fabsf(x);
    float p = -0.0187293f;
    p = fmaf(p, y, 0.0742610f);
    p = fmaf(p, y, -0.2121144f);
    p = fmaf(p, y, 1.5707288f);
    float a = sqrtf(1.0f - y) * p;
    return (x >= 0.0f) ? a : (3.14159265358979f - a);
}

// Winding-angle accumulation for one pixel against kv vertices.
// VP is either an LDS-rooted or global-rooted float2 pointer.
template <typename VP>
__device__ __forceinline__ float winding_sum(VP vsrc, int kv, float mx, float my)
{
    float acc = 0.0f;
    float2 v0 = vsrc[0];
    float dx = v0.x - mx;
    float dy = v0.y - my;
    const float d0x = dx, d0y = dy;            // first diff, for wraparound edge
    float nd2 = fmaf(dx, dx, dy * dy);         // ||diff||^2, carried forward
    const float nd02 = nd2;

    #pragma unroll 4
    for (int k = 0; k < kv - 1; ++k) {
        float2 vn = vsrc[k + 1];
        float rx = vn.x - mx;
        float ry = vn.y - my;
        float cross = dy * rx - dx * ry;       // matches reference sign
        float dot   = fmaf(dx, rx, dy * ry);
        float nr2   = fmaf(rx, rx, ry * ry);
        float cosang = dot * __builtin_amdgcn_rsqf(nd2 * nr2);
        cosang = fminf(fmaxf(cosang, -1.0f + 1e-5f), 1.0f - 1e-5f);
        acc = fmaf(fast_tanh(100000.0f * cross), fast_acos(cosang), acc);
        dx = rx; dy = ry; nd2 = nr2;
    }
    // wraparound edge: (diff_{kv-1}, diff_0)
    {
        float cross = dy * d0x - dx * d0y;
        float dot   = fmaf(dx, d0x, dy * d0y);
        float cosang = dot * __builtin_amdgcn_rsqf(nd2 * nd02);
        cosang = fminf(fmaxf(cosang, -1.0f + 1e-5f), 1.0f - 1e-5f);
        acc = fmaf(fast_tanh(100000.0f * cross), fast_acos(cosang), acc);
    }
    return acc;
}

__global__ __launch_bounds__(BLOCK)
void contour_mask_kernel(const float2* __restrict__ contour,
                         const int* __restrict__ size_ptr,
                         float* __restrict__ out,
                         int out_size, int in0_elems)
{
    __shared__ float2 verts[MAX_KV_LDS];

    const int size     = *size_ptr;          // scalar (wave-uniform) load
    const int S2       = size * size;
    const int bn_total = out_size / S2;
    const int kv       = in0_elems / (bn_total * 2);

    const int idx     = blockIdx.x * BLOCK + threadIdx.x;
    const int bn0     = (blockIdx.x * BLOCK) / S2;              // bn of lane 0
    const int bn_last = (blockIdx.x * BLOCK + BLOCK - 1) / S2;  // bn of last lane
    const bool use_lds = (kv <= MAX_KV_LDS) && (bn0 == bn_last);

    if (use_lds) {
        for (int i = threadIdx.x; i < kv; i += BLOCK)
            verts[i] = contour[(size_t)bn0 * kv + i];
    }
    __syncthreads();

    if (idx >= out_size) return;

    const int bn = idx / S2;
    const int p  = idx - bn * S2;
    const float inv_size = 1.0f / (float)size;
    const int pi = p / size;
    const int pj = p - pi * size;
    // mesh = meshgrid(g, g, 'ij').reshape(-1,2)/size: ch0 = i/size, ch1 = j/size
    const float mx = (float)pi * inv_size;
    const float my = (float)pj * inv_size;

    float acc;
    if (use_lds)
        acc = winding_sum(verts, kv, mx, my);
    else
        acc = winding_sum(contour + (size_t)bn * kv, kv, mx, my);

    // |sum| / (2*pi), clipped to [0, 1]
    float res = fabsf(acc) * 0.15915494309189535f;
    res = fminf(res, 1.0f);
    out[idx] = res;
}

extern "C" void kernel_launch(void* const* d_in, const int* in_sizes, int n_in,
                              void* d_out, int out_size, void* d_ws, size_t ws_size,
                              hipStream_t stream)
{
    const float2* contour  = (const float2*)d_in[0];
    const int*    size_ptr = (const int*)d_in[1];
    float*        out      = (float*)d_out;

    const int blocks = (out_size + BLOCK - 1) / BLOCK;
    contour_mask_kernel<<<blocks, BLOCK, 0, stream>>>(
        contour, size_ptr, out, out_size, in_sizes[0]);
}